// Round 7
// baseline (253.412 us; speedup 1.0000x reference)
//
#include <hip/hip_runtime.h>
#include <math.h>

#define DIN  128
#define DOUT 64
#define SLOT 96   // padded slots per dst; deg ~ Poisson(32), P(any >= 96) ~ 1e-13

typedef __attribute__((ext_vector_type(8))) short  short8;   // 8 bf16 (4 VGPRs)
typedef __attribute__((ext_vector_type(4))) float  floatx4;  // MFMA C/D frag

__device__ inline unsigned short f2bf(float f) {          // RNE bf16 round
    unsigned u = __float_as_uint(f);
    u += 0x7fffu + ((u >> 16) & 1u);
    return (unsigned short)(u >> 16);
}
__device__ inline float bflo(unsigned u) { return __uint_as_float(u << 16); }
__device__ inline float bfhi(unsigned u) { return __uint_as_float(u & 0xffff0000u); }

// ---------------------------------------------------------------------------
// K0: pre-pack W_l / W_r into per-lane MFMA B-fragments (bf16).
// b-frag layout for mfma_f32_16x16x32_bf16: lane holds B[k=quad*8+j][n=lane&15],
// j=0..7.  Packed as 16 B per (mat,kt,nt,lane) so the hot loop loads one
// dwordx4 instead of 8 strided scalars + 8 cvts.
// ---------------------------------------------------------------------------
__global__ void __launch_bounds__(256) pack_k(const float* __restrict__ Wl,
    const float* __restrict__ Wr, uint4* __restrict__ wb)
{
    int t = blockIdx.x * 256 + threadIdx.x;      // [0, 2048)
    if (t >= 2048) return;
    int lane = t & 63;
    int nt   = (t >> 6) & 3;
    int kt   = (t >> 8) & 3;
    int mat  = t >> 10;
    const float* W = mat ? Wr : Wl;
    int n  = nt * 16 + (lane & 15);
    int k0 = kt * 32 + (lane >> 4) * 8;
    unsigned h[8];
    #pragma unroll
    for (int j = 0; j < 8; ++j) h[j] = f2bf(W[(k0 + j) * DOUT + n]);
    uint4 v;
    v.x = h[0] | (h[1] << 16);
    v.y = h[2] | (h[3] << 16);
    v.z = h[4] | (h[5] << 16);
    v.w = h[6] | (h[7] << 16);
    wb[t] = v;
}

// ---------------------------------------------------------------------------
// K1 fused: fill blocks interleaved 1-per-P among MFMA proj blocks.
// Fill: 8 edges/thread, 8 independent atomic->store chains; cnt padded to one
// counter per 64B line.  Proj: each wave computes 16 rows x 64 cols of
// x @ W via 16 mfma_f32_16x16x32_bf16 (4 K-tiles x 4 N-tiles).
//   y  = x @ W_l          -> bf16   (rows < n_src)
//   z  = x @ W_r + b_l    -> fp32 d_out (rows < n_dst; reread by gather_k)
// A-frag: lane reads x[rowTile+(lane&15)][kt*32+(lane>>4)*8+j] (32 B contig).
// C/D: col=lane&15, row=(lane>>4)*4+reg (verified mapping).
// ---------------------------------------------------------------------------
__global__ void __launch_bounds__(256) build_k(
    const int* __restrict__ ei, unsigned* __restrict__ cnt,
    int* __restrict__ slots, const uint4* __restrict__ wb,
    const float* __restrict__ x, const float* __restrict__ bl,
    unsigned short* __restrict__ y, float* __restrict__ zout,
    int E, int nFill, int P, int nyb, int n_src, int n_dst, int cstr)
{
    const int b = blockIdx.x;
    const int fq = b / P;
    const bool isFill = ((b % P) == 0) && (fq < nFill);

    if (isFill) {
        int t = fq * 256 + threadIdx.x;
        int base = t * 8;
        if (base >= E) return;
        if (base + 8 <= E) {
            int4 sa = *(const int4*)(ei + base);
            int4 sb4 = *(const int4*)(ei + base + 4);
            int4 da = *(const int4*)(ei + E + base);
            int4 db = *(const int4*)(ei + E + base + 4);
            unsigned p0 = atomicAdd(&cnt[(size_t)da.x * cstr], 1u);
            unsigned p1 = atomicAdd(&cnt[(size_t)da.y * cstr], 1u);
            unsigned p2 = atomicAdd(&cnt[(size_t)da.z * cstr], 1u);
            unsigned p3 = atomicAdd(&cnt[(size_t)da.w * cstr], 1u);
            unsigned p4 = atomicAdd(&cnt[(size_t)db.x * cstr], 1u);
            unsigned p5 = atomicAdd(&cnt[(size_t)db.y * cstr], 1u);
            unsigned p6 = atomicAdd(&cnt[(size_t)db.z * cstr], 1u);
            unsigned p7 = atomicAdd(&cnt[(size_t)db.w * cstr], 1u);
            if (p0 < SLOT) slots[(size_t)da.x * SLOT + p0] = sa.x;
            if (p1 < SLOT) slots[(size_t)da.y * SLOT + p1] = sa.y;
            if (p2 < SLOT) slots[(size_t)da.z * SLOT + p2] = sa.z;
            if (p3 < SLOT) slots[(size_t)da.w * SLOT + p3] = sa.w;
            if (p4 < SLOT) slots[(size_t)db.x * SLOT + p4] = sb4.x;
            if (p5 < SLOT) slots[(size_t)db.y * SLOT + p5] = sb4.y;
            if (p6 < SLOT) slots[(size_t)db.z * SLOT + p6] = sb4.z;
            if (p7 < SLOT) slots[(size_t)db.w * SLOT + p7] = sb4.w;
        } else {
            for (int i = base; i < E && i < base + 8; ++i) {
                int s = ei[i], d = ei[E + i];
                unsigned p = atomicAdd(&cnt[(size_t)d * cstr], 1u);
                if (p < SLOT) slots[(size_t)d * SLOT + p] = s;
            }
        }
        return;
    }

    // ---- MFMA projection part ----
    const int fillsBefore = (fq + 1 < nFill) ? (fq + 1) : nFill;
    const int pb   = b - fillsBefore;            // dense proj index
    const int wave = threadIdx.x >> 6, lane = threadIdx.x & 63;
    const bool isY = (pb < nyb);
    const int tileBase = (isY ? pb : pb - nyb) * 64 + wave * 16;
    const int nRows = isY ? n_src : n_dst;
    const int q = lane >> 4, n = lane & 15;

    // B-fragments (L2-hot, 16 B each)
    const short8* wfr = (const short8*)(wb + (isY ? 0 : 1024));
    short8 bf[4][4];
    #pragma unroll
    for (int kt = 0; kt < 4; ++kt)
        #pragma unroll
        for (int nt = 0; nt < 4; ++nt)
            bf[kt][nt] = wfr[(kt * 4 + nt) * 64 + lane];

    // A row this lane feeds (clamped for OOB tails; stores are guarded)
    int arow = tileBase + n;
    if (arow >= nRows) arow = nRows - 1;
    const float* xr = x + (size_t)arow * DIN + q * 8;

    floatx4 acc[4] = {{0.f,0.f,0.f,0.f},{0.f,0.f,0.f,0.f},
                      {0.f,0.f,0.f,0.f},{0.f,0.f,0.f,0.f}};
    #pragma unroll
    for (int kt = 0; kt < 4; ++kt) {
        float4 u0 = *(const float4*)(xr + kt * 32);
        float4 u1 = *(const float4*)(xr + kt * 32 + 4);
        short8 a;
        a[0] = (short)f2bf(u0.x); a[1] = (short)f2bf(u0.y);
        a[2] = (short)f2bf(u0.z); a[3] = (short)f2bf(u0.w);
        a[4] = (short)f2bf(u1.x); a[5] = (short)f2bf(u1.y);
        a[6] = (short)f2bf(u1.z); a[7] = (short)f2bf(u1.w);
        acc[0] = __builtin_amdgcn_mfma_f32_16x16x32_bf16(a, bf[kt][0], acc[0], 0, 0, 0);
        acc[1] = __builtin_amdgcn_mfma_f32_16x16x32_bf16(a, bf[kt][1], acc[1], 0, 0, 0);
        acc[2] = __builtin_amdgcn_mfma_f32_16x16x32_bf16(a, bf[kt][2], acc[2], 0, 0, 0);
        acc[3] = __builtin_amdgcn_mfma_f32_16x16x32_bf16(a, bf[kt][3], acc[3], 0, 0, 0);
    }

    if (isY) {
        #pragma unroll
        for (int nt = 0; nt < 4; ++nt)
            #pragma unroll
            for (int r = 0; r < 4; ++r) {
                int row = tileBase + q * 4 + r;
                if (row < nRows)
                    y[(size_t)row * DOUT + nt * 16 + n] = f2bf(acc[nt][r]);
            }
    } else {
        #pragma unroll
        for (int nt = 0; nt < 4; ++nt) {
            const float bias = bl[nt * 16 + n];
            #pragma unroll
            for (int r = 0; r < 4; ++r) {
                int row = tileBase + q * 4 + r;
                if (row < nRows)
                    zout[(size_t)row * DOUT + nt * 16 + n] = acc[nt][r] + bias;
            }
        }
    }
}

// ---------------------------------------------------------------------------
// K2: gather-mean over bf16 y + z + log_softmax.  One wave per dst row.
// <=64 slot indices in one coalesced read; 16-wide inner loop = four 16-lane
// edge-groups x 4 independent accumulator chains; 128 B per edge row.
// ---------------------------------------------------------------------------
__global__ void __launch_bounds__(256) gather_k(
    const unsigned short* __restrict__ y,
    const unsigned* __restrict__ cnt, const int* __restrict__ slots,
    float* __restrict__ out, int n_dst, int cstr)
{
    const int wave = threadIdx.x >> 6, lane = threadIdx.x & 63;
    const int row = blockIdx.x * 4 + wave;
    if (row >= n_dst) return;

    int deg = (int)cnt[(size_t)row * cstr];
    if (deg > SLOT) deg = SLOT;
    const int g = lane >> 4;             // edge subgroup 0..3
    const int qi = (lane & 15) * 2;      // uint index in 32-uint row
    const int q  = (lane & 15) * 4;      // channel quad base
    const unsigned* yw = (const unsigned*)y;

    float4 ac0 = make_float4(0.f,0.f,0.f,0.f);
    float4 ac1 = make_float4(0.f,0.f,0.f,0.f);
    float4 ac2 = make_float4(0.f,0.f,0.f,0.f);
    float4 ac3 = make_float4(0.f,0.f,0.f,0.f);
    const int* srow = slots + (size_t)row * SLOT;

    for (int co = 0; co < deg; co += 64) {
        int rem = deg - co; if (rem > 64) rem = 64;
        int idx = (lane < rem) ? srow[co + lane] : 0;
        for (int i = 0; i < rem; i += 16) {
            int e0 = i + g, e1 = i + 4 + g, e2 = i + 8 + g, e3 = i + 12 + g;
            int s0 = __shfl(idx, e0), s1 = __shfl(idx, e1);
            int s2 = __shfl(idx, e2), s3 = __shfl(idx, e3);
            if (e0 < rem) { uint2 u = *(const uint2*)(yw + (size_t)s0 * 32 + qi);
                ac0.x += bflo(u.x); ac0.y += bfhi(u.x);
                ac0.z += bflo(u.y); ac0.w += bfhi(u.y); }
            if (e1 < rem) { uint2 u = *(const uint2*)(yw + (size_t)s1 * 32 + qi);
                ac1.x += bflo(u.x); ac1.y += bfhi(u.x);
                ac1.z += bflo(u.y); ac1.w += bfhi(u.y); }
            if (e2 < rem) { uint2 u = *(const uint2*)(yw + (size_t)s2 * 32 + qi);
                ac2.x += bflo(u.x); ac2.y += bfhi(u.x);
                ac2.z += bflo(u.y); ac2.w += bfhi(u.y); }
            if (e3 < rem) { uint2 u = *(const uint2*)(yw + (size_t)s3 * 32 + qi);
                ac3.x += bflo(u.x); ac3.y += bfhi(u.x);
                ac3.z += bflo(u.y); ac3.w += bfhi(u.y); }
        }
    }
    float4 acc;
    acc.x = (ac0.x + ac1.x) + (ac2.x + ac3.x);
    acc.y = (ac0.y + ac1.y) + (ac2.y + ac3.y);
    acc.z = (ac0.z + ac1.z) + (ac2.z + ac3.z);
    acc.w = (ac0.w + ac1.w) + (ac2.w + ac3.w);

    acc.x += __shfl_xor(acc.x, 32); acc.y += __shfl_xor(acc.y, 32);
    acc.z += __shfl_xor(acc.z, 32); acc.w += __shfl_xor(acc.w, 32);
    acc.x += __shfl_xor(acc.x, 16); acc.y += __shfl_xor(acc.y, 16);
    acc.z += __shfl_xor(acc.z, 16); acc.w += __shfl_xor(acc.w, 16);

    const float scale = 1.0f / (float)(deg > 0 ? deg : 1);
    const float4 zv = *(const float4*)(out + (size_t)row * DOUT + q);
    float4 v;
    v.x = acc.x * scale + zv.x;
    v.y = acc.y * scale + zv.y;
    v.z = acc.z * scale + zv.z;
    v.w = acc.w * scale + zv.w;

    float m = fmaxf(fmaxf(v.x, v.y), fmaxf(v.z, v.w));
    for (int o = 8; o >= 1; o >>= 1) m = fmaxf(m, __shfl_xor(m, o));
    float s = expf(v.x - m) + expf(v.y - m) + expf(v.z - m) + expf(v.w - m);
    for (int o = 8; o >= 1; o >>= 1) s += __shfl_xor(s, o);
    const float lse = m + logf(s);

    if (lane < 16) {
        float4 o4;
        o4.x = v.x - lse; o4.y = v.y - lse; o4.z = v.z - lse; o4.w = v.w - lse;
        *(float4*)(out + (size_t)row * DOUT + q) = o4;
    }
}

extern "C" void kernel_launch(void* const* d_in, const int* in_sizes, int n_in,
                              void* d_out, int out_size, void* d_ws, size_t ws_size,
                              hipStream_t stream)
{
    const float* x  = (const float*)d_in[0];
    const float* Wl = (const float*)d_in[1];
    const float* bl = (const float*)d_in[2];
    const float* Wr = (const float*)d_in[3];
    const int*   ei = (const int*)d_in[4];

    const int E     = in_sizes[4] / 2;     // 1,600,000
    const int n_src = in_sizes[0] / DIN;   // 100,000
    const int n_dst = out_size / DOUT;     // 50,000

    // layout: cnt (n_dst*cstr u32) | slots (n_dst*SLOT int) | y (n_src*64 bf16)
    //         | wb (2048 uint4 packed W frags)
    int cstr = 16;                         // one counter per 64B line
    size_t need16 = (size_t)n_dst * cstr * 4 + (size_t)n_dst * SLOT * 4
                  + (size_t)n_src * DOUT * 2 + 2048 * 16;
    if (need16 > ws_size) cstr = 1;

    unsigned*       cnt   = (unsigned*)d_ws;
    int*            slots = (int*)(cnt + (size_t)n_dst * cstr);
    unsigned short* yb    = (unsigned short*)(slots + (size_t)n_dst * SLOT);
    uint4*          wb    = (uint4*)(yb + (size_t)n_src * DOUT);

    hipMemsetAsync(cnt, 0, (size_t)n_dst * cstr * sizeof(unsigned), stream);
    pack_k<<<8, 256, 0, stream>>>(Wl, Wr, wb);

    int nFill = (E + 2047) / 2048;         // 8 edges/thread  (782)
    int nyb = (n_src + 63) / 64;           // 1563
    int nzb = (n_dst + 63) / 64;           // 782
    int total = nFill + nyb + nzb;         // 3127
    int P = (total + nFill - 1) / nFill;   // 1 fill block per P blocks

    build_k<<<total, 256, 0, stream>>>(
        ei, cnt, slots, wb, x, bl, yb, (float*)d_out,
        E, nFill, P, nyb, n_src, n_dst, cstr);

    int gG = (n_dst + 3) / 4;              // 12500
    gather_k<<<gG, 256, 0, stream>>>(yb, cnt, slots, (float*)d_out, n_dst, cstr);
}

// Round 9
// 244.885 us; speedup vs baseline: 1.0348x; 1.0348x over previous
//
#include <hip/hip_runtime.h>
#include <math.h>

#define DIN  128
#define DOUT 64

typedef __attribute__((ext_vector_type(8))) short  short8;   // 8 bf16 (4 VGPRs)
typedef __attribute__((ext_vector_type(4))) float  floatx4;  // MFMA C/D frag

__device__ inline unsigned short f2bf(float f) {          // RNE bf16 round
    unsigned u = __float_as_uint(f);
    u += 0x7fffu + ((u >> 16) & 1u);
    return (unsigned short)(u >> 16);
}
__device__ inline float bflo(unsigned u) { return __uint_as_float(u << 16); }
__device__ inline float bfhi(unsigned u) { return __uint_as_float(u & 0xffff0000u); }

// ---------------------------------------------------------------------------
// K0: pre-pack W_l / W_r into per-lane MFMA B-fragments (bf16), 16 B/lane.
// ---------------------------------------------------------------------------
__global__ void __launch_bounds__(256) pack_k(const float* __restrict__ Wl,
    const float* __restrict__ Wr, uint4* __restrict__ wb)
{
    int t = blockIdx.x * 256 + threadIdx.x;      // [0, 2048)
    if (t >= 2048) return;
    int lane = t & 63;
    int nt   = (t >> 6) & 3;
    int kt   = (t >> 8) & 3;
    int mat  = t >> 10;
    const float* W = mat ? Wr : Wl;
    int n  = nt * 16 + (lane & 15);
    int k0 = kt * 32 + (lane >> 4) * 8;
    unsigned h[8];
    #pragma unroll
    for (int j = 0; j < 8; ++j) h[j] = f2bf(W[(k0 + j) * DOUT + n]);
    uint4 v;
    v.x = h[0] | (h[1] << 16);
    v.y = h[2] | (h[3] << 16);
    v.z = h[4] | (h[5] << 16);
    v.w = h[6] | (h[7] << 16);
    wb[t] = v;
}

// ---------------------------------------------------------------------------
// K1 fused: EXACT interleave — grid = nFill*P, fill iff b%P==0 (exactly nFill
// fill blocks by construction; R8's ceil-based P dropped 16% of fill quota).
// Proj dense index pb = b - fq - 1, guarded against nProj.
//
// Fill with SUB-BINNED counters: dst d, sub u = edge_index & (nsub-1) ->
// counter cnt[(d*nsub+u)*cstr] (own 64B line), private sub-bin
// slots[d*nsub*cap + u*cap + p].  Per-ADDRESS atomic conflict depth drops
// 32 -> ~8 (nsub=4) — the hypothesis for the ~120us fill floor of R3-R7.
//
// Proj: per wave 16 rows x 64 cols of x @ W via 16 mfma_f32_16x16x32_bf16.
//   y = x @ W_l -> bf16 ; z = x @ W_r + b_l -> fp32 d_out (reread by K2).
// ---------------------------------------------------------------------------
__global__ void __launch_bounds__(256) build_k(
    const int* __restrict__ ei, unsigned* __restrict__ cnt,
    int* __restrict__ slots, const uint4* __restrict__ wb,
    const float* __restrict__ x, const float* __restrict__ bl,
    unsigned short* __restrict__ y, float* __restrict__ zout,
    int E, int nFill, int P, int nProj, int nyb, int n_src, int n_dst,
    int nsub, int cap, int cstr)
{
    const int b = blockIdx.x;
    const int fq = b / P;
    const bool isFill = ((b % P) == 0);          // exactly nFill blocks

    if (isFill) {
        int t = fq * 256 + threadIdx.x;
        int base = t * 4;
        if (base >= E) return;
        const int sm = nsub - 1;        // sub mask (nsub is 1/2/4)
        const int rowlen = nsub * cap;
        if (base + 4 <= E) {
            int4 s4 = *(const int4*)(ei + base);
            int4 d4 = *(const int4*)(ei + E + base);
            int u0 = (base + 0) & sm, u1 = (base + 1) & sm;
            int u2 = (base + 2) & sm, u3 = (base + 3) & sm;
            unsigned p0 = atomicAdd(&cnt[(size_t)(d4.x * nsub + u0) * cstr], 1u);
            unsigned p1 = atomicAdd(&cnt[(size_t)(d4.y * nsub + u1) * cstr], 1u);
            unsigned p2 = atomicAdd(&cnt[(size_t)(d4.z * nsub + u2) * cstr], 1u);
            unsigned p3 = atomicAdd(&cnt[(size_t)(d4.w * nsub + u3) * cstr], 1u);
            if (p0 < (unsigned)cap) slots[(size_t)d4.x * rowlen + u0 * cap + p0] = s4.x;
            if (p1 < (unsigned)cap) slots[(size_t)d4.y * rowlen + u1 * cap + p1] = s4.y;
            if (p2 < (unsigned)cap) slots[(size_t)d4.z * rowlen + u2 * cap + p2] = s4.z;
            if (p3 < (unsigned)cap) slots[(size_t)d4.w * rowlen + u3 * cap + p3] = s4.w;
        } else {
            for (int i = base; i < E && i < base + 4; ++i) {
                int s = ei[i], d = ei[E + i];
                int u = i & sm;
                unsigned p = atomicAdd(&cnt[(size_t)(d * nsub + u) * cstr], 1u);
                if (p < (unsigned)cap) slots[(size_t)d * rowlen + u * cap + p] = s;
            }
        }
        return;
    }

    // ---- MFMA projection part ----
    const int pb = b - fq - 1;                   // dense proj index (exact)
    if (pb >= nProj) return;
    const int wave = threadIdx.x >> 6, lane = threadIdx.x & 63;
    const bool isY = (pb < nyb);
    const int tileBase = (isY ? pb : pb - nyb) * 64 + wave * 16;
    const int nRows = isY ? n_src : n_dst;
    const int q = lane >> 4, n = lane & 15;

    const short8* wfr = (const short8*)(wb + (isY ? 0 : 1024));
    short8 bf[4][4];
    #pragma unroll
    for (int kt = 0; kt < 4; ++kt)
        #pragma unroll
        for (int nt = 0; nt < 4; ++nt)
            bf[kt][nt] = wfr[(kt * 4 + nt) * 64 + lane];

    int arow = tileBase + n;
    if (arow >= nRows) arow = nRows - 1;
    const float* xr = x + (size_t)arow * DIN + q * 8;

    floatx4 acc[4] = {{0.f,0.f,0.f,0.f},{0.f,0.f,0.f,0.f},
                      {0.f,0.f,0.f,0.f},{0.f,0.f,0.f,0.f}};
    #pragma unroll
    for (int kt = 0; kt < 4; ++kt) {
        float4 u0 = *(const float4*)(xr + kt * 32);
        float4 u1 = *(const float4*)(xr + kt * 32 + 4);
        short8 a;
        a[0] = (short)f2bf(u0.x); a[1] = (short)f2bf(u0.y);
        a[2] = (short)f2bf(u0.z); a[3] = (short)f2bf(u0.w);
        a[4] = (short)f2bf(u1.x); a[5] = (short)f2bf(u1.y);
        a[6] = (short)f2bf(u1.z); a[7] = (short)f2bf(u1.w);
        acc[0] = __builtin_amdgcn_mfma_f32_16x16x32_bf16(a, bf[kt][0], acc[0], 0, 0, 0);
        acc[1] = __builtin_amdgcn_mfma_f32_16x16x32_bf16(a, bf[kt][1], acc[1], 0, 0, 0);
        acc[2] = __builtin_amdgcn_mfma_f32_16x16x32_bf16(a, bf[kt][2], acc[2], 0, 0, 0);
        acc[3] = __builtin_amdgcn_mfma_f32_16x16x32_bf16(a, bf[kt][3], acc[3], 0, 0, 0);
    }

    if (isY) {
        #pragma unroll
        for (int nt = 0; nt < 4; ++nt)
            #pragma unroll
            for (int r = 0; r < 4; ++r) {
                int row = tileBase + q * 4 + r;
                if (row < nRows)
                    y[(size_t)row * DOUT + nt * 16 + n] = f2bf(acc[nt][r]);
            }
    } else {
        #pragma unroll
        for (int nt = 0; nt < 4; ++nt) {
            const float bias = bl[nt * 16 + n];
            #pragma unroll
            for (int r = 0; r < 4; ++r) {
                int row = tileBase + q * 4 + r;
                if (row < nRows)
                    zout[(size_t)row * DOUT + nt * 16 + n] = acc[nt][r] + bias;
            }
        }
    }
}

// ---------------------------------------------------------------------------
// K2: gather-mean over bf16 y + z + log_softmax.  One wave per dst row.
// Sub-binned slot rows: ordinal o -> sub s via cumulative counts (3 cmps),
// addr = row*nsub*cap + s*cap + (o - cum[s]).  16-wide inner loop: four
// 16-lane edge-groups x 4 independent accumulator chains, 128 B/edge row.
// ---------------------------------------------------------------------------
__global__ void __launch_bounds__(256) gather_k(
    const unsigned short* __restrict__ y,
    const unsigned* __restrict__ cnt, const int* __restrict__ slots,
    float* __restrict__ out, int n_dst, int nsub, int cap, int cstr)
{
    const int wave = threadIdx.x >> 6, lane = threadIdx.x & 63;
    const int row = blockIdx.x * 4 + wave;
    if (row >= n_dst) return;

    int c[4];
    #pragma unroll
    for (int s = 0; s < 4; ++s) {
        int v = 0;
        if (s < nsub) {
            v = (int)cnt[(size_t)(row * nsub + s) * cstr];
            if (v > cap) v = cap;
        }
        c[s] = v;
    }
    const int cum1 = c[0], cum2 = c[0] + c[1], cum3 = c[0] + c[1] + c[2];
    const int deg  = cum3 + c[3];

    const int g = lane >> 4;             // edge subgroup 0..3
    const int qi = (lane & 15) * 2;      // uint index in 32-uint row
    const int q  = (lane & 15) * 4;      // channel quad base
    const unsigned* yw = (const unsigned*)y;

    float4 ac0 = make_float4(0.f,0.f,0.f,0.f);
    float4 ac1 = make_float4(0.f,0.f,0.f,0.f);
    float4 ac2 = make_float4(0.f,0.f,0.f,0.f);
    float4 ac3 = make_float4(0.f,0.f,0.f,0.f);
    const int* srow = slots + (size_t)row * nsub * cap;

    for (int co = 0; co < deg; co += 64) {
        int rem = deg - co; if (rem > 64) rem = 64;
        int idx = 0;
        if (lane < rem) {
            int o = co + lane;
            int s = (o >= cum1) + (o >= cum2) + (o >= cum3);
            int base = (s == 0) ? 0 : ((s == 1) ? cum1 : ((s == 2) ? cum2 : cum3));
            idx = srow[s * cap + (o - base)];
        }
        for (int i = 0; i < rem; i += 16) {
            int e0 = i + g, e1 = i + 4 + g, e2 = i + 8 + g, e3 = i + 12 + g;
            int s0 = __shfl(idx, e0), s1 = __shfl(idx, e1);
            int s2 = __shfl(idx, e2), s3 = __shfl(idx, e3);
            if (e0 < rem) { uint2 u = *(const uint2*)(yw + (size_t)s0 * 32 + qi);
                ac0.x += bflo(u.x); ac0.y += bfhi(u.x);
                ac0.z += bflo(u.y); ac0.w += bfhi(u.y); }
            if (e1 < rem) { uint2 u = *(const uint2*)(yw + (size_t)s1 * 32 + qi);
                ac1.x += bflo(u.x); ac1.y += bfhi(u.x);
                ac1.z += bflo(u.y); ac1.w += bfhi(u.y); }
            if (e2 < rem) { uint2 u = *(const uint2*)(yw + (size_t)s2 * 32 + qi);
                ac2.x += bflo(u.x); ac2.y += bfhi(u.x);
                ac2.z += bflo(u.y); ac2.w += bfhi(u.y); }
            if (e3 < rem) { uint2 u = *(const uint2*)(yw + (size_t)s3 * 32 + qi);
                ac3.x += bflo(u.x); ac3.y += bfhi(u.x);
                ac3.z += bflo(u.y); ac3.w += bfhi(u.y); }
        }
    }
    float4 acc;
    acc.x = (ac0.x + ac1.x) + (ac2.x + ac3.x);
    acc.y = (ac0.y + ac1.y) + (ac2.y + ac3.y);
    acc.z = (ac0.z + ac1.z) + (ac2.z + ac3.z);
    acc.w = (ac0.w + ac1.w) + (ac2.w + ac3.w);

    acc.x += __shfl_xor(acc.x, 32); acc.y += __shfl_xor(acc.y, 32);
    acc.z += __shfl_xor(acc.z, 32); acc.w += __shfl_xor(acc.w, 32);
    acc.x += __shfl_xor(acc.x, 16); acc.y += __shfl_xor(acc.y, 16);
    acc.z += __shfl_xor(acc.z, 16); acc.w += __shfl_xor(acc.w, 16);

    const float scale = 1.0f / (float)(deg > 0 ? deg : 1);
    const float4 zv = *(const float4*)(out + (size_t)row * DOUT + q);
    float4 v;
    v.x = acc.x * scale + zv.x;
    v.y = acc.y * scale + zv.y;
    v.z = acc.z * scale + zv.z;
    v.w = acc.w * scale + zv.w;

    float m = fmaxf(fmaxf(v.x, v.y), fmaxf(v.z, v.w));
    for (int o = 8; o >= 1; o >>= 1) m = fmaxf(m, __shfl_xor(m, o));
    float s = expf(v.x - m) + expf(v.y - m) + expf(v.z - m) + expf(v.w - m);
    for (int o = 8; o >= 1; o >>= 1) s += __shfl_xor(s, o);
    const float lse = m + logf(s);

    if (lane < 16) {
        float4 o4;
        o4.x = v.x - lse; o4.y = v.y - lse; o4.z = v.z - lse; o4.w = v.w - lse;
        *(float4*)(out + (size_t)row * DOUT + q) = o4;
    }
}

extern "C" void kernel_launch(void* const* d_in, const int* in_sizes, int n_in,
                              void* d_out, int out_size, void* d_ws, size_t ws_size,
                              hipStream_t stream)
{
    const float* x  = (const float*)d_in[0];
    const float* Wl = (const float*)d_in[1];
    const float* bl = (const float*)d_in[2];
    const float* Wr = (const float*)d_in[3];
    const int*   ei = (const int*)d_in[4];

    const int E     = in_sizes[4] / 2;     // 1,600,000
    const int n_src = in_sizes[0] / DIN;   // 100,000
    const int n_dst = out_size / DOUT;     // 50,000

    // widest sub-binning that fits ws:
    //   A: nsub=4, cap=40 (57.7 MB)  B: nsub=2, cap=56 (41.7 MB)
    //   C: nsub=1, cap=96 (35.2 MB, R7 layout)
    const int cstr = 16;                   // one counter per 64B line
    int nsub = 4, cap = 40;
    auto need = [&](int ns, int cp) {
        return (size_t)n_dst * ns * cstr * 4 + (size_t)n_dst * ns * cp * 4
             + (size_t)n_src * DOUT * 2 + 2048 * 16;
    };
    if (need(4, 40) > ws_size) { nsub = 2; cap = 56; }
    if (need(nsub, cap) > ws_size) { nsub = 1; cap = 96; }

    unsigned*       cnt   = (unsigned*)d_ws;
    int*            slots = (int*)(cnt + (size_t)n_dst * nsub * cstr);
    unsigned short* yb    = (unsigned short*)(slots + (size_t)n_dst * nsub * cap);
    uint4*          wb    = (uint4*)(yb + (size_t)n_src * DOUT);

    hipMemsetAsync(cnt, 0, (size_t)n_dst * nsub * cstr * sizeof(unsigned), stream);
    pack_k<<<8, 256, 0, stream>>>(Wl, Wr, wb);

    int nFill = (E + 1023) / 1024;         // 4 edges/thread  (1563)
    int nyb = (n_src + 63) / 64;           // 1563
    int nzb = (n_dst + 63) / 64;           // 782
    int nProj = nyb + nzb;                 // 2345
    // exact interleave: grid = nFill*P, fill iff b%P==0; proj pb = b-fq-1
    int P = 1 + (nProj + nFill - 1) / nFill;   // 3
    int total = nFill * P;                     // 4689

    build_k<<<total, 256, 0, stream>>>(
        ei, cnt, slots, wb, x, bl, yb, (float*)d_out,
        E, nFill, P, nProj, nyb, n_src, n_dst, nsub, cap, cstr);

    int gG = (n_dst + 3) / 4;              // 12500
    gather_k<<<gG, 256, 0, stream>>>(yb, cnt, slots, (float*)d_out, n_dst,
                                     nsub, cap, cstr);
}